// Round 12
// baseline (104.138 us; speedup 1.0000x reference)
//
#include <hip/hip_runtime.h>

// Problem constants (fixed by setup_inputs)
constexpr int H_OUT = 256;
constexpr int D     = 256;   // W_in * K_gather

typedef __bf16 bf16x8 __attribute__((ext_vector_type(8)));
typedef float  f32x16 __attribute__((ext_vector_type(16)));

// fp32 -> bf16, round-to-nearest-even
__device__ __forceinline__ ushort f2bf(float f) {
    uint u = __float_as_uint(f);
    u = (u + 0x7FFFu + ((u >> 16) & 1u)) >> 16;
    return (ushort)u;
}
__device__ __forceinline__ uint pack2(float a, float b) {
    return (uint)f2bf(a) | ((uint)f2bf(b) << 16);
}
__device__ __forceinline__ uint2 pack4(float4 v) {
    uint2 r; r.x = pack2(v.x, v.y); r.y = pack2(v.z, v.w); return r;
}
__device__ __forceinline__ bf16x8 packfrag(float4 lo, float4 hi4) {
    uint4 o;
    o.x = pack2(lo.x, lo.y);  o.y = pack2(lo.z, lo.w);
    o.z = pack2(hi4.x, hi4.y); o.w = pack2(hi4.z, hi4.w);
    return __builtin_bit_cast(bf16x8, o);
}

// v6: latency-bound fix. NO x-LDS, NO main-loop barriers.
// Block = (h, batch-quarter of 128 rows), 4 waves; wave = 32 rows x 64 cols.
// W[h] -> LDS bf16 once (1 barrier total); x A-fragments stream global->reg
// with a depth-2 pipeline; grid 1024 = exactly 4 blocks/CU at
// __launch_bounds__(256,4) -> 16 waves/CU (2x the v5 TLP).
__global__ __launch_bounds__(256, 4) void sparse_linear_v6(
    const float* __restrict__ x,      // [512, 128, 64] fp32
    const int*   __restrict__ mask,   // [256, 4]
    const float* __restrict__ W,      // [256, 64, 256] fp32
    const float* __restrict__ bias,   // [256, 64]
    float*       __restrict__ out)    // [512, 256, 64] fp32
{
    const int bx   = blockIdx.x;
    const int h    = ((bx >> 5) << 3) | (bx & 7);  // h%8 == bx%8 (XCD); 4 bq-blocks of an h adjacent
    const int bq   = (bx >> 3) & 3;
    const int tid  = threadIdx.x;
    const int lane = tid & 63, wid = tid >> 6;
    const int rowl = lane & 31, hi = lane >> 5;

    // W tile: 64 rows x 32 slots of 16B (8 bf16), XOR-swizzled slot ^= (row&15).
    // This exact write/read pattern measured SQ_LDS_BANK_CONFLICT = 0 in r9.
    __shared__ float4 Wls[64 * 32];   // 32 KB -> 4 blocks/CU fits 160 KB

    int mq[4];
    #pragma unroll
    for (int q = 0; q < 4; ++q) mq[q] = mask[h * 4 + q];

    // wave's batch rows: bq*128 + wid*32 + rowl
    const float* xb = x + (size_t)(bq * 128 + wid * 32 + rowl) * (128 * 64);

    // ---- prefetch A-fragments for ks=0,1 (issued before W stage: latency
    // hides under the 16 W loads + cvt). Per lane: 8 consecutive floats at
    // gathered k-offset; lane halves (hi=0/1) share 64B lines.
    float4 pa0, pb0, pa1, pb1;
    {
        const int k00 = hi * 8;                      // ks=0
        const float* p0 = xb + mq[0] * 64 + k00;     // k00>>6 == 0
        pa0 = ((const float4*)p0)[0]; pb0 = ((const float4*)p0)[1];
        const int k01 = 16 + hi * 8;                 // ks=1
        const float* p1 = xb + mq[0] * 64 + k01;     // k01 in [16,31] -> chunk 0
        pa1 = ((const float4*)p1)[0]; pb1 = ((const float4*)p1)[1];
    }

    // ---- stage W[h] -> bf16 LDS, coalesced (wave reads 1 KB contiguous/instr)
    {
        const int c    = tid & 63;   // float4 col (k = 4c)
        const int wrow = tid >> 6;
        const float4* wsrc = (const float4*)(W + (size_t)h * 64 * D);
        #pragma unroll
        for (int p = 0; p < 16; ++p) {
            const int R = p * 4 + wrow;
            const float4 v = wsrc[(size_t)R * 64 + c];
            *((uint2*)&Wls[R * 32 + ((c >> 1) ^ (R & 15))] + (c & 1)) = pack4(v);
        }
    }
    __syncthreads();   // the ONLY barrier

    const int xv = rowl & 15;        // swizzle key; same for both col-subtiles
    f32x16 acc0 = {}, acc1 = {};

    #pragma unroll
    for (int ks = 0; ks < 16; ++ks) {          // fully unrolled: parity static
        const bf16x8 a = (ks & 1) ? packfrag(pa1, pb1) : packfrag(pa0, pb0);

        if (ks + 2 < 16) {                      // depth-2 refill (static)
            const int kn = (ks + 2) * 16 + hi * 8;
            const float* pn = xb + mq[kn >> 6] * 64 + (kn & 63);
            if (ks & 1) { pa1 = ((const float4*)pn)[0]; pb1 = ((const float4*)pn)[1]; }
            else        { pa0 = ((const float4*)pn)[0]; pb0 = ((const float4*)pn)[1]; }
        }

        const int s = ks * 2 + hi;
        const bf16x8 b0 = __builtin_bit_cast(bf16x8, Wls[rowl * 32 + (s ^ xv)]);
        const bf16x8 b1 = __builtin_bit_cast(bf16x8, Wls[(32 + rowl) * 32 + (s ^ xv)]);
        acc0 = __builtin_amdgcn_mfma_f32_32x32x16_bf16(a, b0, acc0, 0, 0, 0);
        acc1 = __builtin_amdgcn_mfma_f32_32x32x16_bf16(a, b1, acc1, 0, 0, 0);
    }

    // ---- epilogue: C/D layout col=lane&31, row=(reg&3)+8*(reg>>2)+4*hi
    const float bv0 = bias[h * 64 + rowl];
    const float bv1 = bias[h * 64 + 32 + rowl];
    #pragma unroll
    for (int reg = 0; reg < 16; ++reg) {
        const int rl = (reg & 3) + 8 * (reg >> 2) + 4 * hi;
        const size_t b = (size_t)bq * 128 + wid * 32 + rl;
        float* o = out + (b * H_OUT + h) * 64;
        o[rowl]      = acc0[reg] + bv0;
        o[32 + rowl] = acc1[reg] + bv1;
    }
}

extern "C" void kernel_launch(void* const* d_in, const int* in_sizes, int n_in,
                              void* d_out, int out_size, void* d_ws, size_t ws_size,
                              hipStream_t stream) {
    const float* x    = (const float*)d_in[0];
    const int*   mask = (const int*)d_in[1];
    const float* W    = (const float*)d_in[2];
    const float* bias = (const float*)d_in[3];
    float* out = (float*)d_out;

    dim3 grid(1024);   // (h, bq) XCD-mapped; exactly 4 blocks/CU, one round
    dim3 block(256);
    sparse_linear_v6<<<grid, block, 0, stream>>>(x, mask, W, bias, out);
}

// Round 14
// 102.529 us; speedup vs baseline: 1.0157x; 1.0157x over previous
//
#include <hip/hip_runtime.h>

// Problem constants (fixed by setup_inputs)
constexpr int H_OUT = 256;
constexpr int D     = 256;   // W_in * K_gather

typedef __bf16 bf16x8 __attribute__((ext_vector_type(8)));
typedef float  f32x16 __attribute__((ext_vector_type(16)));

// fp32 -> bf16, round-to-nearest-even (numerics identical to rounds 3-12)
__device__ __forceinline__ ushort f2bf(float f) {
    uint u = __float_as_uint(f);
    u = (u + 0x7FFFu + ((u >> 16) & 1u)) >> 16;
    return (ushort)u;
}
__device__ __forceinline__ uint pack2(float a, float b) {
    return (uint)f2bf(a) | ((uint)f2bf(b) << 16);
}

// ---- prep: one-pass cvt of x (to fragment-major transposed layout) and W ----
// xbt 16B-chunk index: ((b5*128 + hin)*8 + w8)*32 + rowl,  b = b5*32+rowl, w = w8*8..+7
// => main-kernel A-fragment load (lanes rowl,hi) is 1KB CONTIGUOUS per wave.
__global__ __launch_bounds__(256) void prep_bf16(
    const float* __restrict__ x,   // [512,128,64]
    const float* __restrict__ W,   // [256,64,256]
    ushort* __restrict__ xbt,      // 8.4 MB
    ushort* __restrict__ Wb)       // 8.4 MB
{
    const int bx = blockIdx.x;
    const int t  = (bx & 1023) * 256 + threadIdx.x;   // 0..262143 per path
    if (bx < 1024) {
        // x path: read 64B/lane (full lines; lanes l,l+32 adjacent 64B), write 2x16B
        const int rowl = t & 31, w16 = (t >> 5) & 3, hin = (t >> 7) & 127, b5 = t >> 14;
        const float4* src = (const float4*)(x + (((size_t)(b5 * 32 + rowl) * 128 + hin) * 64 + w16 * 16));
        const float4 v0 = src[0], v1 = src[1], v2 = src[2], v3 = src[3];
        uint4 lo, hi4;
        lo.x  = pack2(v0.x, v0.y); lo.y  = pack2(v0.z, v0.w);
        lo.z  = pack2(v1.x, v1.y); lo.w  = pack2(v1.z, v1.w);
        hi4.x = pack2(v2.x, v2.y); hi4.y = pack2(v2.z, v2.w);
        hi4.z = pack2(v3.x, v3.y); hi4.w = pack2(v3.z, v3.w);
        const size_t d16 = ((size_t)(b5 * 128 + hin) * 8 + w16 * 2) * 32 + rowl;
        ((uint4*)xbt)[d16]      = lo;    // lanes rowl fast -> 512B contiguous
        ((uint4*)xbt)[d16 + 32] = hi4;   // w8+1 block
    } else {
        // W path: linear cvt, 16 elems/thread (64B read, 32B write, coalesced)
        const size_t u = (size_t)t * 16;
        const float4* src = (const float4*)(W + u);
        const float4 v0 = src[0], v1 = src[1], v2 = src[2], v3 = src[3];
        uint4 o0, o1;
        o0.x = pack2(v0.x, v0.y); o0.y = pack2(v0.z, v0.w);
        o0.z = pack2(v1.x, v1.y); o0.w = pack2(v1.z, v1.w);
        o1.x = pack2(v2.x, v2.y); o1.y = pack2(v2.z, v2.w);
        o1.z = pack2(v3.x, v3.y); o1.w = pack2(v3.z, v3.w);
        ((uint4*)Wb)[2 * t]     = o0;
        ((uint4*)Wb)[2 * t + 1] = o1;
    }
}

// v7: v6 skeleton (no main-loop barriers, 4 blocks/CU = 16 waves/CU) with
// bf16 inputs: 1 coalesced 16B x-load + 2 ds_read_b128 + 2 MFMA per k-step,
// zero pack VALU in the hot loop.
__global__ __launch_bounds__(256, 4) void sparse_linear_v7(
    const ushort* __restrict__ xbt,   // fragment-major bf16 x
    const ushort* __restrict__ Wb,    // [256,64,256] bf16
    const int*    __restrict__ mask,  // [256,4]
    const float*  __restrict__ bias,  // [256,64]
    float*        __restrict__ out)   // [512,256,64] fp32
{
    const int bx   = blockIdx.x;
    const int h    = ((bx >> 5) << 3) | (bx & 7);  // h%8 == bx%8 (XCD); 4 bq-blocks adjacent
    const int bq   = (bx >> 3) & 3;
    const int tid  = threadIdx.x;
    const int lane = tid & 63, wid = tid >> 6;
    const int rowl = lane & 31, hi = lane >> 5;
    const int b5   = bq * 4 + wid;                 // wave's 32-row group

    // W tile: 64 rows x 32 slots of 16B, XOR-swizzled slot ^= (row&15)
    // (read pattern measured SQ_LDS_BANK_CONFLICT = 0 in r9)
    __shared__ float4 Wls[64 * 32];   // 32 KB

    int mq[4];
    #pragma unroll
    for (int q = 0; q < 4; ++q) mq[q] = mask[h * 4 + q];

    // A-fragment address (16B units): ks -> q = ks>>2, w8 = (ks&3)*2 + hi
    const uint4* xb16 = (const uint4*)xbt;
    #define XIDX(ks) (((size_t)(b5 * 128 + mq[(ks) >> 2]) * 8 + ((ks) & 3) * 2 + hi) * 32 + rowl)

    // prefetch ks=0,1 (latency hides under W stage)
    uint4 pa0 = xb16[XIDX(0)];
    uint4 pa1 = xb16[XIDX(1)];

    // stage W[h] from bf16: 8 passes, lanes read row-contiguous 512B; no cvt
    {
        const int c2 = tid & 31, R0 = tid >> 5;
        const uint4* wsrc = (const uint4*)(Wb + (size_t)h * 64 * D);
        #pragma unroll
        for (int p = 0; p < 8; ++p) {
            const int R = p * 8 + R0;
            const uint4 v = wsrc[R * 32 + c2];
            Wls[R * 32 + (c2 ^ (R & 15))] = __builtin_bit_cast(float4, v);
        }
    }
    __syncthreads();   // the ONLY barrier

    const int xv = rowl & 15;
    f32x16 acc0 = {}, acc1 = {};

    #pragma unroll
    for (int ks = 0; ks < 16; ++ks) {
        const bf16x8 a = __builtin_bit_cast(bf16x8, (ks & 1) ? pa1 : pa0);

        if (ks + 2 < 16) {                      // depth-2 refill (static parity)
            const uint4 pn = xb16[XIDX(ks + 2)];
            if (ks & 1) pa1 = pn; else pa0 = pn;
        }

        const int s = ks * 2 + hi;
        const bf16x8 b0 = __builtin_bit_cast(bf16x8, Wls[rowl * 32 + (s ^ xv)]);
        const bf16x8 b1 = __builtin_bit_cast(bf16x8, Wls[(32 + rowl) * 32 + (s ^ xv)]);
        acc0 = __builtin_amdgcn_mfma_f32_32x32x16_bf16(a, b0, acc0, 0, 0, 0);
        acc1 = __builtin_amdgcn_mfma_f32_32x32x16_bf16(a, b1, acc1, 0, 0, 0);
    }
    #undef XIDX

    // epilogue: C/D layout col=lane&31, row=(reg&3)+8*(reg>>2)+4*hi
    const float bv0 = bias[h * 64 + rowl];
    const float bv1 = bias[h * 64 + 32 + rowl];
    #pragma unroll
    for (int reg = 0; reg < 16; ++reg) {
        const int rl = (reg & 3) + 8 * (reg >> 2) + 4 * hi;
        const size_t b = (size_t)bq * 128 + wid * 32 + rl;
        float* o = out + (b * H_OUT + h) * 64;
        o[rowl]      = acc0[reg] + bv0;
        o[32 + rowl] = acc1[reg] + bv1;
    }
}

extern "C" void kernel_launch(void* const* d_in, const int* in_sizes, int n_in,
                              void* d_out, int out_size, void* d_ws, size_t ws_size,
                              hipStream_t stream) {
    const float* x    = (const float*)d_in[0];
    const int*   mask = (const int*)d_in[1];
    const float* W    = (const float*)d_in[2];
    const float* bias = (const float*)d_in[3];
    float*  out = (float*)d_out;
    ushort* xbt = (ushort*)d_ws;                       // 8,388,608 B
    ushort* Wb  = (ushort*)((char*)d_ws + 8388608);    // 8,388,608 B

    prep_bf16<<<dim3(2048), dim3(256), 0, stream>>>(x, W, xbt, Wb);
    sparse_linear_v7<<<dim3(1024), dim3(256), 0, stream>>>(xbt, Wb, mask, bias, out);
}